// Round 8
// baseline (4650609.375 us; speedup 1.0000x reference)
//
#include <hip/hip_runtime.h>
#include <math.h>

// LSTM encoder: B=32, S=512, E=512, H=1024, G=4H=4096.
// Round 8: per-XCD replicated scan — ZERO cross-XCD traffic in the recurrence.
//   - 256 WGs x 1024 thr, LDS 131.6KB -> exactly 1 WG/CU -> 32 WGs/XCD
//   - WG reads HW_REG_XCC_ID, grabs slot 0..31 in its XCD -> owns 32 units
//   - each XCD computes the FULL h[t+1] (8x redundant compute, ~0.3us)
//   - intra-XCD sync: plain h stores (->L2) + flag store; consumers poll
//     flags with sc0 loads (bypass L1, hit L2), first-touch h ring reads
//   - h image stored XOR-chunk-swizzled by producer; MFMA A-frags ds_read
//     conflict-free; W persistent in 128 VGPRs/lane; xg in f16

#define B_ 32
#define S_ 512
#define E_ 512
#define H_ 1024
#define G_ 4096
#define NWG 256
#define RTHR 1024
#define BH_ (B_ * H_)
#define SMEM_BYTES (65536 + 66048 + 16)   // hlds 64K + part[4][32][129] + info

typedef _Float16 f16x8 __attribute__((ext_vector_type(8)));
typedef _Float16 f16x4 __attribute__((ext_vector_type(4)));
typedef float f32x4 __attribute__((ext_vector_type(4)));

__device__ __forceinline__ float sigmoidf_(float x) {
  return 1.0f / (1.0f + __expf(-x));
}
__device__ __forceinline__ float tanhf_(float x) {
  return 1.0f - 2.0f / (__expf(2.0f * x) + 1.0f);
}

// ---------------- one-time: Whh f32[1024][4096] -> Wt f16[4096][1024] ----------------
__global__ __launch_bounds__(256) void wt_kernel(
    const float* __restrict__ Whh, _Float16* __restrict__ Wt)
{
  __shared__ float Lt[64][65];
  const int c0 = blockIdx.x * 64;
  const int k0 = blockIdx.y * 64;
  const int tid = threadIdx.x;
  const int colL = tid & 63;
  const int rq = tid >> 6;
#pragma unroll 4
  for (int p = 0; p < 16; ++p) {
    int r = p * 4 + rq;
    Lt[colL][r] = Whh[(size_t)(k0 + r) * G_ + c0 + colL];
  }
  __syncthreads();
  const int col = tid >> 2;
  const int kq = (tid & 3) * 16;
  _Float16 tmp[16];
#pragma unroll
  for (int i = 0; i < 16; ++i) tmp[i] = (_Float16)Lt[col][kq + i];
  *(f16x8*)(Wt + (size_t)(c0 + col) * H_ + k0 + kq)     = *(f16x8*)&tmp[0];
  *(f16x8*)(Wt + (size_t)(c0 + col) * H_ + k0 + kq + 8) = *(f16x8*)&tmp[8];
}

// ---------------- Phase A: x-gates GEMM (f32 compute, f16 output) ----------------
__global__ __launch_bounds__(256) void xgates_gemm(
    const int* __restrict__ src, const float* __restrict__ emb,
    const float* __restrict__ Wih, const float* __restrict__ bih,
    const float* __restrict__ bhh, _Float16* __restrict__ xg, int t0)
{
  __shared__ float As[16][132];
  __shared__ float Bs[16][132];
  __shared__ int rowOff[128];

  const int tid = threadIdx.x;
  const int row0 = blockIdx.y * 128;
  const int col0 = blockIdx.x * 128;

  if (tid < 128) {
    int r = row0 + tid;
    int t = t0 + (r >> 5);
    int b = r & 31;
    rowOff[tid] = src[b * S_ + t];
  }
  __syncthreads();

  const int tx = tid & 15, ty = tid >> 4;
  float acc[8][8];
#pragma unroll
  for (int i = 0; i < 8; ++i)
#pragma unroll
    for (int j = 0; j < 8; ++j) acc[i][j] = 0.f;

  const int arl = tid >> 2;
  const int akq = (tid & 3) * 4;
  const int bkr = tid >> 4;
  const int bc  = (tid & 15) * 4;

  for (int k0 = 0; k0 < E_; k0 += 16) {
#pragma unroll
    for (int p = 0; p < 2; ++p) {
      int rl = arl + p * 64;
      float4 v = *(const float4*)(emb + (size_t)rowOff[rl] * E_ + k0 + akq);
      As[akq + 0][rl] = v.x;
      As[akq + 1][rl] = v.y;
      As[akq + 2][rl] = v.z;
      As[akq + 3][rl] = v.w;
    }
#pragma unroll
    for (int p = 0; p < 2; ++p) {
      int c = bc + p * 64;
      *(float4*)&Bs[bkr][c] =
          *(const float4*)(Wih + (size_t)(k0 + bkr) * G_ + col0 + c);
    }
    __syncthreads();
#pragma unroll
    for (int k = 0; k < 16; ++k) {
      float av[8], bv[8];
      *(float4*)&av[0] = *(const float4*)&As[k][ty * 8];
      *(float4*)&av[4] = *(const float4*)&As[k][ty * 8 + 4];
      *(float4*)&bv[0] = *(const float4*)&Bs[k][tx * 4];
      *(float4*)&bv[4] = *(const float4*)&Bs[k][tx * 4 + 64];
#pragma unroll
      for (int i = 0; i < 8; ++i)
#pragma unroll
        for (int j = 0; j < 8; ++j) acc[i][j] = fmaf(av[i], bv[j], acc[i][j]);
    }
    __syncthreads();
  }

  const int ca = col0 + tx * 4;
  const int cb = ca + 64;
  float4 b1 = *(const float4*)(bih + ca);
  float4 b2 = *(const float4*)(bhh + ca);
  float4 b3 = *(const float4*)(bih + cb);
  float4 b4 = *(const float4*)(bhh + cb);
  float4 biasA = make_float4(b1.x + b2.x, b1.y + b2.y, b1.z + b2.z, b1.w + b2.w);
  float4 biasB = make_float4(b3.x + b4.x, b3.y + b4.y, b3.z + b4.z, b3.w + b4.w);
#pragma unroll
  for (int i = 0; i < 8; ++i) {
    int r = row0 + ty * 8 + i;
    _Float16* dst = xg + (size_t)r * G_;
    f16x4 oa = { (_Float16)(acc[i][0] + biasA.x), (_Float16)(acc[i][1] + biasA.y),
                 (_Float16)(acc[i][2] + biasA.z), (_Float16)(acc[i][3] + biasA.w) };
    f16x4 ob = { (_Float16)(acc[i][4] + biasB.x), (_Float16)(acc[i][5] + biasB.y),
                 (_Float16)(acc[i][6] + biasB.z), (_Float16)(acc[i][7] + biasB.w) };
    *(f16x4*)(dst + ca) = oa;
    *(f16x4*)(dst + cb) = ob;
  }
}

// ---------------- Phase R: per-XCD replicated recurrent kernel ----------------
// WG owns 32 units (128 gate cols). 16 waves = bt2 x kq4 x ctp2; per wave:
// 8 k-steps x 4 c-tiles = 32 MFMA 16x16x32; W frags 128 VGPR; A from swizzled LDS.
__global__ __launch_bounds__(RTHR, 4) void lstm_xcd(
    const _Float16* __restrict__ Wt, const _Float16* __restrict__ xg,
    unsigned short* hring, float* cbuf, unsigned* flg, unsigned* cnt,
    float* out, int t0, int nt)
{
  extern __shared__ char smem[];
  float* part = (float*)(smem + 65536);                 // [4][32][129]
  volatile int* shinfo = (volatile int*)(smem + 65536 + 66048);

  const int tid  = threadIdx.x;
  const int wave = tid >> 6;
  const int lane = tid & 63;

  if (tid == 0) {
    unsigned xcc;
    asm volatile("s_getreg_b32 %0, hwreg(20, 0, 32)" : "=s"(xcc));
    int xcdv = (int)(xcc & 7u);
    unsigned s = __hip_atomic_fetch_add(cnt + xcdv, 1u, __ATOMIC_RELAXED,
                                        __HIP_MEMORY_SCOPE_AGENT);
    shinfo[0] = xcdv;
    shinfo[1] = (int)(s & 31u);
  }
  __syncthreads();
  const int xcd  = shinfo[0];
  const int slot = shinfo[1];
  const int U0 = slot * 32;

  const int lrow = lane & 15;
  const int lhi  = lane >> 4;
  const int bt   = wave >> 3;          // 0..1 (batch half)
  const int kq   = (wave >> 1) & 3;    // 0..3 (K quarter, 256 wide)
  const int ctp  = wave & 1;           // 0..1 (col-tile pair)

  // persistent W fragments bf[ct][s]: 32 x f16x8 = 128 VGPR/lane
  f16x8 bf[4][8];
#pragma unroll
  for (int ct = 0; ct < 4; ++ct) {
    const int ctg = ctp * 4 + ct;                       // 0..7 (16-col tile)
    const int gcol = (ctg >> 1) * H_ + U0 + (ctg & 1) * 16 + lrow;
    const _Float16* wp = Wt + (size_t)gcol * H_ + kq * 256 + lhi * 8;
#pragma unroll
    for (int s = 0; s < 8; ++s)
      bf[ct][s] = *(const f16x8*)(wp + s * 32);
  }

  const int eb = tid >> 5;             // epilogue: batch 0..31
  const int eu = tid & 31;             // epilogue: unit 0..31
  float cstate = cbuf[(size_t)eb * H_ + U0 + eu];

  float xv0, xv1, xv2, xv3;
  {
    const _Float16* xp = xg + (size_t)eb * G_ + U0 + eu;
    xv0 = (float)xp[0];      xv1 = (float)xp[H_];
    xv2 = (float)xp[2 * H_]; xv3 = (float)xp[3 * H_];
  }

  for (int t = t0; t < t0 + nt; ++t) {
    const int lt = t - t0;
    const char* hg = (const char*)(hring + (size_t)lt * BH_);      // first touch
    char* hw = (char*)(hring + (size_t)((lt == nt - 1) ? 0 : lt + 1) * BH_);

    // ---- gate: wave 0 polls this XCD's 32 flags (sc0: bypass L1, hit L2) ----
    if (wave == 0) {
      const unsigned* fp = flg + (size_t)t * 256 + xcd * 32 + (lane & 31);
      int guard = 0;
      for (;;) {
        unsigned v;
        asm volatile("global_load_dword %0, %1, off sc0\n\t"
                     "s_waitcnt vmcnt(0)"
                     : "=v"(v) : "v"(fp) : "memory");
        if (__all(v != 0u)) break;
        __builtin_amdgcn_s_sleep(1);
        if (++guard > (1 << 18)) break;   // bounded: fail loud, never hang
      }
    }
    __syncthreads();   // A: h[t] visible in this XCD's L2

    // ---- stage swizzled h image -> LDS (64KB, global_load_lds w16) ----
#pragma unroll
    for (int i = 0; i < 4; ++i) {
      const int off = (wave * 4 + i) * 1024;
      __builtin_amdgcn_global_load_lds(
          (const __attribute__((address_space(1))) void*)(hg + off + lane * 16),
          (__attribute__((address_space(3))) void*)(smem + off), 16, 0, 0);
    }
    __syncthreads();   // B: hlds ready (vmcnt drained)

    // ---- MFMA: 8 k-steps x 4 c-tiles, A-frag ds_read conflict-free ----
    f32x4 acc[4] = {{0,0,0,0},{0,0,0,0},{0,0,0,0},{0,0,0,0}};
    const int krow = bt * 16 + lrow;
#pragma unroll
    for (int s = 0; s < 8; ++s) {
      const int kc = kq * 32 + s * 4 + lhi;             // 16B chunk index (k>>3)
      const f16x8 af =
          *(const f16x8*)(smem + krow * 2048 + ((kc ^ (krow & 7)) << 4));
#pragma unroll
      for (int ct = 0; ct < 4; ++ct)
        acc[ct] = __builtin_amdgcn_mfma_f32_16x16x32_f16(af, bf[ct][s], acc[ct],
                                                         0, 0, 0);
    }

    // next-step xg prefetch (L2/L3, independent of h)
    float xn0, xn1, xn2, xn3;
    {
      const int nlt = (lt == nt - 1) ? lt : lt + 1;
      const _Float16* xp = xg + ((size_t)nlt * B_ + eb) * G_ + U0 + eu;
      xn0 = (float)xp[0];      xn1 = (float)xp[H_];
      xn2 = (float)xp[2 * H_]; xn3 = (float)xp[3 * H_];
    }

    // ---- K-partials -> LDS ----
#pragma unroll
    for (int ct = 0; ct < 4; ++ct) {
      const int col = (ctp * 4 + ct) * 16 + lrow;
      const int rb = (kq * 32 + bt * 16 + lhi * 4) * 129 + col;
#pragma unroll
      for (int r = 0; r < 4; ++r)
        part[rb + r * 129] = acc[ct][r];
    }
    __syncthreads();   // C

    // ---- reduce + gates + state update (all 1024 threads) ----
    {
      float g0 = xv0, g1 = xv1, g2 = xv2, g3 = xv3;
#pragma unroll
      for (int k = 0; k < 4; ++k) {
        const float* pp = part + (size_t)(k * 32 + eb) * 129 + eu;
        g0 += pp[0];
        g1 += pp[32];
        g2 += pp[64];
        g3 += pp[96];
      }
      const float ig = sigmoidf_(g0);
      const float fg = sigmoidf_(g1);
      const float gg = tanhf_(g2);
      const float og = sigmoidf_(g3);
      cstate = fg * cstate + ig * gg;
      const float hval = og * tanhf_(cstate);
      if ((t & 7) == xcd)                      // out dedup: XCD x owns t%8==x
        out[((size_t)eb * S_ + t) * H_ + U0 + eu] = hval;
      const _Float16 hf = (_Float16)hval;
      unsigned short hb;
      __builtin_memcpy(&hb, &hf, 2);
      const int gk = U0 + eu;
      *(unsigned short*)(hw + eb * 2048 + ((((gk >> 3) ^ (eb & 7)) << 4)) +
                         ((gk & 7) << 1)) = hb;        // swizzled h image, plain store
    }
    __syncthreads();   // D: all waves' h stores acked in L2

    if (tid == 0)
      flg[(size_t)(t + 1) * 256 + xcd * 32 + slot] = 1u;   // plain store -> L2

    xv0 = xn0; xv1 = xn1; xv2 = xn2; xv3 = xn3;
  }

  cbuf[(size_t)eb * H_ + U0 + eu] = cstate;   // 8 XCDs write identical values
}

// ---------------- host ----------------
extern "C" void kernel_launch(void* const* d_in, const int* in_sizes, int n_in,
                              void* d_out, int out_size, void* d_ws, size_t ws_size,
                              hipStream_t stream) {
  const int*   src = (const int*)d_in[0];
  const float* emb = (const float*)d_in[1];
  const float* Wih = (const float*)d_in[2];
  const float* Whh = (const float*)d_in[3];
  const float* bih = (const float*)d_in[4];
  const float* bhh = (const float*)d_in[5];
  float* out = (float*)d_out;

  // ws: [cbuf 128K][flg 513*256*4][cnt 256B][Wt 8M][hring][xg f16]
  char* ws = (char*)d_ws;
  float*    cbuf = (float*)ws;                                   // 131072
  unsigned* flg  = (unsigned*)(ws + 131072);                     // 525312
  unsigned* cntb = (unsigned*)(ws + 131072 + 525312);            // 256
  const size_t stateBytes = 131072 + 525312 + 256;               // 656640
  _Float16* Wt = (_Float16*)(ws + stateBytes);                   // 8 MB
  const size_t wtBytes = (size_t)G_ * H_ * 2;

  int chunk = 0;
  const int cand[4] = {512, 256, 128, 64};
  for (int ci = 0; ci < 4; ++ci) {
    size_t need = stateBytes + wtBytes + (size_t)(cand[ci] + 1) * (BH_ * 2)
                  + (size_t)cand[ci] * B_ * G_ * 2;
    if (need <= ws_size) { chunk = cand[ci]; break; }
  }
  if (chunk == 0) return;  // fail loud

  unsigned short* hring = (unsigned short*)(ws + stateBytes + wtBytes);
  _Float16* xg = (_Float16*)(ws + stateBytes + wtBytes
                             + (size_t)(chunk + 1) * (BH_ * 2));

  (void)hipMemsetAsync(ws, 0, stateBytes, stream);   // c0, flags, slot counters
  (void)hipMemsetAsync(flg, 1, 1024, stream);        // seed flags[t=0][*][*]
  (void)hipMemsetAsync(hring, 0, BH_ * 2, stream);   // h0 = 0 (ring slot 0)

  (void)hipFuncSetAttribute((const void*)lstm_xcd,
                            hipFuncAttributeMaxDynamicSharedMemorySize,
                            160 * 1024);

  wt_kernel<<<dim3(64, 16), 256, 0, stream>>>(Whh, Wt);

  int d = 0;
  for (int t0 = 0; t0 < S_; t0 += chunk, ++d) {
    dim3 ga(G_ / 128, (chunk * B_) / 128);
    xgates_gemm<<<ga, 256, 0, stream>>>(src, emb, Wih, bih, bhh, xg, t0);

    int nt = chunk;
    unsigned* cnt = cntb + 8 * d;
    void* args[] = {(void*)&Wt, (void*)&xg, (void*)&hring, (void*)&cbuf,
                    (void*)&flg, (void*)&cnt, (void*)&out, (void*)&t0, (void*)&nt};
    (void)hipLaunchCooperativeKernel((void*)lstm_xcd, dim3(NWG), dim3(RTHR),
                                     args, (unsigned)SMEM_BYTES, stream);
  }
}

// Round 9
// 2654.666 us; speedup vs baseline: 1751.8624x; 1751.8624x over previous
//
#include <hip/hip_runtime.h>
#include <math.h>

// LSTM encoder: B=32, S=512, E=512, H=1024, G=4H=4096.
// Round 9: revert to r5-proven MALL coherence; surgical latency + throughput:
//   - lstm: flag barrier (write-through store + cache-bypass poll; validated
//     primitives only) replaces grp/root RMW tree: 2 fewer MALL hops/step
//   - xg in f16 (halves lstm fetch)
//   - xgates: f16 MFMA GEMM (gather_a + 128x128 tile), bias in acc-init
//   - one-time transposes: Whh->Wt[4096][1024], Wih->Wt2[4096][512] (f16)

#define B_ 32
#define S_ 512
#define E_ 512
#define H_ 1024
#define G_ 4096
#define NWG 256
#define RTHR 512
#define BH_ (B_ * H_)
#define XGPAD 40   // LDS row stride (f16): 80B = 16B-aligned, 2-way banks max

typedef _Float16 f16x8 __attribute__((ext_vector_type(8)));
typedef _Float16 f16x4 __attribute__((ext_vector_type(4)));
typedef float f32x4 __attribute__((ext_vector_type(4)));

__device__ __forceinline__ float sigmoidf_(float x) {
  return 1.0f / (1.0f + __expf(-x));
}
__device__ __forceinline__ float tanhf_(float x) {
  return 1.0f - 2.0f / (__expf(2.0f * x) + 1.0f);
}

// ---- one-time: W f32[K][4096] -> Wt f16[4096][K] (transpose + convert) ----
__global__ __launch_bounds__(256) void wt_kernel(
    const float* __restrict__ W, _Float16* __restrict__ Wt, int K)
{
  __shared__ float Lt[64][65];
  const int c0 = blockIdx.x * 64;
  const int k0 = blockIdx.y * 64;
  const int tid = threadIdx.x;
  const int colL = tid & 63;
  const int rq = tid >> 6;
#pragma unroll 4
  for (int p = 0; p < 16; ++p) {
    int r = p * 4 + rq;
    Lt[colL][r] = W[(size_t)(k0 + r) * G_ + c0 + colL];
  }
  __syncthreads();
  const int col = tid >> 2;
  const int kq = (tid & 3) * 16;
  _Float16 tmp[16];
#pragma unroll
  for (int i = 0; i < 16; ++i) tmp[i] = (_Float16)Lt[col][kq + i];
  *(f16x8*)(Wt + (size_t)(c0 + col) * K + k0 + kq)     = *(f16x8*)&tmp[0];
  *(f16x8*)(Wt + (size_t)(c0 + col) * K + k0 + kq + 8) = *(f16x8*)&tmp[8];
}

// ---- gather embedding rows -> f16 A[chunk*32][512] ----
__global__ __launch_bounds__(128) void gather_a(
    const int* __restrict__ src, const float* __restrict__ emb,
    _Float16* __restrict__ A, int t0)
{
  const int r = blockIdx.x;
  const int t = t0 + (r >> 5), b = r & 31;
  const int vrow = src[b * S_ + t];
  const float4 v = *(const float4*)(emb + (size_t)vrow * E_ + threadIdx.x * 4);
  f16x4 o = { (_Float16)v.x, (_Float16)v.y, (_Float16)v.z, (_Float16)v.w };
  *(f16x4*)(A + (size_t)r * E_ + threadIdx.x * 4) = o;
}

// ---- Phase A: x-gates f16 MFMA GEMM: xg = A[rows][512] * Wt2^T + bias ----
__global__ __launch_bounds__(256) void xgates_mfma(
    const _Float16* __restrict__ A, const _Float16* __restrict__ Bw,
    const float* __restrict__ bih, const float* __restrict__ bhh,
    _Float16* __restrict__ xg)
{
  __shared__ _Float16 Al[128][XGPAD];
  __shared__ _Float16 Bl[128][XGPAD];
  const int tid = threadIdx.x;
  const int row0 = blockIdx.y * 128;
  const int col0 = blockIdx.x * 128;
  const int wave = tid >> 6, lane = tid & 63;
  const int wm = wave >> 1, wn = wave & 1;
  const int lrow = lane & 15, lhi = lane >> 4;

  float bias[4];
#pragma unroll
  for (int n = 0; n < 4; ++n) {
    int c = col0 + wn * 64 + n * 16 + lrow;
    bias[n] = bih[c] + bhh[c];
  }
  f32x4 acc[4][4];
#pragma unroll
  for (int m = 0; m < 4; ++m)
#pragma unroll
    for (int n = 0; n < 4; ++n)
      acc[m][n] = (f32x4){bias[n], bias[n], bias[n], bias[n]};

  for (int kt = 0; kt < E_ / 32; ++kt) {
#pragma unroll
    for (int p = 0; p < 2; ++p) {     // 512 16B-chunks per tile pair, 2/thread
      int cch = tid * 2 + p;
      int rr = cch >> 2, kc = cch & 3;
      *(f16x8*)&Al[rr][kc * 8] =
          *(const f16x8*)(A + (size_t)(row0 + rr) * E_ + kt * 32 + kc * 8);
      *(f16x8*)&Bl[rr][kc * 8] =
          *(const f16x8*)(Bw + (size_t)(col0 + rr) * E_ + kt * 32 + kc * 8);
    }
    __syncthreads();
    f16x8 af[4], bfr[4];
#pragma unroll
    for (int m = 0; m < 4; ++m)
      af[m] = *(const f16x8*)&Al[wm * 64 + m * 16 + lrow][lhi * 8];
#pragma unroll
    for (int n = 0; n < 4; ++n)
      bfr[n] = *(const f16x8*)&Bl[wn * 64 + n * 16 + lrow][lhi * 8];
#pragma unroll
    for (int m = 0; m < 4; ++m)
#pragma unroll
      for (int n = 0; n < 4; ++n)
        acc[m][n] = __builtin_amdgcn_mfma_f32_16x16x32_f16(af[m], bfr[n],
                                                           acc[m][n], 0, 0, 0);
    __syncthreads();
  }
  // D layout (r5-validated): col = lane&15, row = (lane>>4)*4 + reg
#pragma unroll
  for (int m = 0; m < 4; ++m)
#pragma unroll
    for (int n = 0; n < 4; ++n) {
      const int ccol = col0 + wn * 64 + n * 16 + lrow;
#pragma unroll
      for (int r = 0; r < 4; ++r) {
        const int rrow = row0 + wm * 64 + m * 16 + lhi * 4 + r;
        xg[(size_t)rrow * G_ + ccol] = (_Float16)acc[m][n][r];
      }
    }
}

// ---- Phase R: persistent MFMA recurrent kernel (r5 body + flag barrier) ----
__global__ __launch_bounds__(RTHR) void lstm_mfma(
    const _Float16* __restrict__ Wt, const _Float16* __restrict__ xg,
    unsigned short* hring, float* cbuf, unsigned* flg,
    float* out, int t0, int nt)
{
  __shared__ float red[8 * 32 * 17];   // [wave][b][c] stride-17

  const int wg = blockIdx.x;
  const int tid = threadIdx.x;
  const int J0 = 4 * ((wg & 7) * 32 + (wg >> 3));   // XCD-contiguous hidden blocks

  const int wave = tid >> 6;
  const int lane = tid & 63;
  const int lrow = lane & 15;
  const int lhi  = lane >> 4;
  const int Kw   = wave * 128;
  const int gcol = (lrow >> 2) * H_ + J0 + (lrow & 3);

  f16x8 bf[4];
#pragma unroll
  for (int s = 0; s < 4; ++s)
    bf[s] = *(const f16x8*)(Wt + (size_t)gcol * H_ + Kw + s * 32 + lhi * 8);

  const int bq = tid >> 2, jq = tid & 3;   // epilogue mapping (tid<128)
  float cstate = 0.f;
  if (tid < 128) cstate = cbuf[(size_t)bq * H_ + J0 + jq];

  float xv0 = 0.f, xv1 = 0.f, xv2 = 0.f, xv3 = 0.f;
  if (tid < 128) {
    const _Float16* xp = xg + (size_t)bq * G_ + J0 + jq;
    xv0 = (float)xp[0];      xv1 = (float)xp[H_];
    xv2 = (float)xp[2 * H_]; xv3 = (float)xp[3 * H_];
  }

  for (int t = t0; t < t0 + nt; ++t) {
    const int lt = t - t0;
    const _Float16* hrd = (const _Float16*)hring + (size_t)lt * BH_;   // first touch
    unsigned short* hwr = hring + (size_t)((lt == nt - 1) ? 0 : lt + 1) * BH_;

    // ---- gate: wave 0 polls all 256 flags for step t (4 per lane) ----
    if (wave == 0) {
      const unsigned* fp = flg + (size_t)t * 256 + lane * 4;
      int guard = 0;
      for (;;) {
        unsigned a0 = __hip_atomic_load(fp + 0, __ATOMIC_RELAXED, __HIP_MEMORY_SCOPE_AGENT);
        unsigned a1 = __hip_atomic_load(fp + 1, __ATOMIC_RELAXED, __HIP_MEMORY_SCOPE_AGENT);
        unsigned a2 = __hip_atomic_load(fp + 2, __ATOMIC_RELAXED, __HIP_MEMORY_SCOPE_AGENT);
        unsigned a3 = __hip_atomic_load(fp + 3, __ATOMIC_RELAXED, __HIP_MEMORY_SCOPE_AGENT);
        if (__all((a0 & a1 & a2 & a3) != 0u)) break;
        __builtin_amdgcn_s_sleep(1);
        if (++guard > (1 << 22)) break;   // bounded: fail loud, never hang
      }
    }
    __syncthreads();   // A: h[t] visible (flags observed)

    f32x4 acc0 = {0.f, 0.f, 0.f, 0.f};
    f32x4 acc1 = {0.f, 0.f, 0.f, 0.f};
#pragma unroll
    for (int s = 0; s < 4; ++s) {
      f16x8 a0 = *(const f16x8*)(hrd + (size_t)lrow * H_ + Kw + s * 32 + lhi * 8);
      f16x8 a1 = *(const f16x8*)(hrd + (size_t)(16 + lrow) * H_ + Kw + s * 32 + lhi * 8);
      acc0 = __builtin_amdgcn_mfma_f32_16x16x32_f16(a0, bf[s], acc0, 0, 0, 0);
      acc1 = __builtin_amdgcn_mfma_f32_16x16x32_f16(a1, bf[s], acc1, 0, 0, 0);
    }

    // next-step xg prefetch (hidden under reduce+store+sync)
    float xn0 = 0.f, xn1 = 0.f, xn2 = 0.f, xn3 = 0.f;
    if (tid < 128) {
      const int nlt = (lt == nt - 1) ? lt : lt + 1;
      const _Float16* xp = xg + ((size_t)nlt * B_ + bq) * G_ + J0 + jq;
      xn0 = (float)xp[0];      xn1 = (float)xp[H_];
      xn2 = (float)xp[2 * H_]; xn3 = (float)xp[3 * H_];
    }

#pragma unroll
    for (int r = 0; r < 4; ++r) {
      red[(wave * 32 + lhi * 4 + r) * 17 + lrow]      = acc0[r];
      red[(wave * 32 + 16 + lhi * 4 + r) * 17 + lrow] = acc1[r];
    }
    __syncthreads();   // B

    if (tid < 128) {
      float g0 = xv0, g1 = xv1, g2 = xv2, g3 = xv3;
#pragma unroll
      for (int w = 0; w < 8; ++w) {
        const float* rp = red + (w * 32 + bq) * 17;
        g0 += rp[jq];
        g1 += rp[4 + jq];
        g2 += rp[8 + jq];
        g3 += rp[12 + jq];
      }
      float ig = sigmoidf_(g0);
      float fg = sigmoidf_(g1);
      float gg = tanhf_(g2);
      float og = sigmoidf_(g3);
      cstate = fg * cstate + ig * gg;
      float hval = og * tanhf_(cstate);
      out[((size_t)bq * S_ + t) * H_ + J0 + jq] = hval;   // f32, pre-quantization
      _Float16 hf = (_Float16)hval;
      unsigned short hb;
      __builtin_memcpy(&hb, &hf, 2);
      __hip_atomic_store(hwr + (size_t)bq * H_ + J0 + jq, hb,
                         __ATOMIC_RELAXED, __HIP_MEMORY_SCOPE_AGENT);
    }
    __syncthreads();   // C: all h stores acked at MALL (vmcnt drained per wave)

    if (tid == 0)      // publish: single write-through flag store, no ack wait
      __hip_atomic_store(flg + (size_t)(t + 1) * 256 + wg, 1u,
                         __ATOMIC_RELAXED, __HIP_MEMORY_SCOPE_AGENT);

    xv0 = xn0; xv1 = xn1; xv2 = xn2; xv3 = xn3;
  }

  if (tid < 128) cbuf[(size_t)bq * H_ + J0 + jq] = cstate;
}

// ---------------- host ----------------
extern "C" void kernel_launch(void* const* d_in, const int* in_sizes, int n_in,
                              void* d_out, int out_size, void* d_ws, size_t ws_size,
                              hipStream_t stream) {
  const int*   src = (const int*)d_in[0];
  const float* emb = (const float*)d_in[1];
  const float* Wih = (const float*)d_in[2];
  const float* Whh = (const float*)d_in[3];
  const float* bih = (const float*)d_in[4];
  const float* bhh = (const float*)d_in[5];
  float* out = (float*)d_out;

  // ws: [cbuf 128K][flg (S+1)*256*4][Wt 8M][Wt2 4M][hring][Af16][xg f16]
  char* ws = (char*)d_ws;
  float*    cbuf = (float*)ws;                          // 131072
  unsigned* flg  = (unsigned*)(ws + 131072);            // 513*256*4 = 525312
  const size_t stateBytes = 131072 + 525312;            // 656384
  _Float16* Wt  = (_Float16*)(ws + stateBytes);                    // 8 MB
  _Float16* Wt2 = (_Float16*)(ws + stateBytes + 8388608);          // 4 MB
  const size_t fixedBytes = stateBytes + 8388608 + 4194304;

  int chunk = 0;
  const int cand[4] = {512, 256, 128, 64};
  for (int ci = 0; ci < 4; ++ci) {
    size_t need = fixedBytes + (size_t)(cand[ci] + 1) * (BH_ * 2)   // hring
                  + (size_t)cand[ci] * B_ * E_ * 2                  // Af16
                  + (size_t)cand[ci] * B_ * G_ * 2;                 // xg f16
    if (need <= ws_size) { chunk = cand[ci]; break; }
  }
  if (chunk == 0) return;  // fail loud

  unsigned short* hring = (unsigned short*)(ws + fixedBytes);
  _Float16* Af16 = (_Float16*)(ws + fixedBytes + (size_t)(chunk + 1) * (BH_ * 2));
  _Float16* xg   = (_Float16*)(ws + fixedBytes + (size_t)(chunk + 1) * (BH_ * 2)
                               + (size_t)chunk * B_ * E_ * 2);

  (void)hipMemsetAsync(ws, 0, stateBytes, stream);   // c0 = 0, all flags = 0
  (void)hipMemsetAsync(flg, 1, 1024, stream);        // flags[t=0][0..255] nonzero
  (void)hipMemsetAsync(hring, 0, BH_ * 2, stream);   // h0 = 0 (ring slot 0)

  int K1 = H_, K2 = E_;
  wt_kernel<<<dim3(64, 16), 256, 0, stream>>>(Whh, Wt, K1);
  wt_kernel<<<dim3(64, 8), 256, 0, stream>>>(Wih, Wt2, K2);

  for (int t0 = 0; t0 < S_; t0 += chunk) {
    gather_a<<<dim3(chunk * B_), 128, 0, stream>>>(src, emb, Af16, t0);
    xgates_mfma<<<dim3(G_ / 128, chunk * B_ / 128), 256, 0, stream>>>(
        Af16, Wt2, bih, bhh, xg);

    int nt = chunk;
    void* args[] = {(void*)&Wt, (void*)&xg, (void*)&hring, (void*)&cbuf,
                    (void*)&flg, (void*)&out, (void*)&t0, (void*)&nt};
    (void)hipLaunchCooperativeKernel((void*)lstm_mfma, dim3(NWG), dim3(RTHR),
                                     args, 0u, stream);
  }
}